// Round 8
// baseline (332.639 us; speedup 1.0000x reference)
//
#include <hip/hip_runtime.h>
#include <hip/hip_bf16.h>

// Problem constants (from reference setup_inputs: b=4, s=4096, d=2048, CAPACITY=0.5)
#define BATCH 4
#define SEQ   4096
#define DMODEL 2048
#define KSEL  2048            // max(1, int(SEQ*0.5))
#define NBLK  1024            // 4 blocks/CU x 256 CUs (co-resident by construction)
#define BLOCKS_PER_BATCH 256  // 4096 rows / 16 rows-per-block

typedef float f32x4 __attribute__((ext_vector_type(4)));

// ---------------------------------------------------------------------------
// Fused kernel: phase A computes logits+weights (16 rows/block, exact R4
// 2-row-per-wave summation order -> bit-identical logits for top-k safety),
// then a device-scope per-batch arrival barrier, then phase B:
//   blocks 0..511 : top-K mask (half a 64-element chunk each; per-thread
//                   work identical to R4's best K2)
//   block  512    : aux variance
//   blocks 513+   : exit (free CUs for phase B)
// Deadlock safety: consumers spin on PER-BATCH counters; consumer block r
// needs batch r>>7, produced by blocks [batch*256, batch*256+256). With
// ~in-order dispatch this pipelines even if only 1-2 blocks/CU are resident;
// __launch_bounds__(256,4) additionally targets full 1024-block residency.
// ---------------------------------------------------------------------------
__global__ __launch_bounds__(256, 4) void fused_kernel(
    const float* __restrict__ x,
    const float* __restrict__ gate_w,
    float* __restrict__ logits,          // d_ws
    unsigned int* __restrict__ ctr,      // d_ws + 64KiB, memset to 0 per call
    float* __restrict__ mask,            // d_out
    float* __restrict__ weights,         // d_out + 16384
    float* __restrict__ aux)             // d_out + 32768
{
    const int tid  = threadIdx.x;
    const int wave = tid >> 6;
    const int lane = tid & 63;
    const int blk  = blockIdx.x;
    const int mybatch = blk >> 8;        // 16 rows/block, 256 blocks/batch

    __shared__ float L[SEQ];             // 16 KiB (phase B)
    __shared__ int sh_gt[32][9];         // stride 9 -> conflict-free combines
    __shared__ int sh_eq[32][9];
    __shared__ double shv[8];

    // ======================= Phase A: logits ===============================
    const f32x4* wr = reinterpret_cast<const f32x4*>(gate_w);
    f32x4 wv[8];
#pragma unroll
    for (int t = 0; t < 8; ++t) wv[t] = wr[t * 64 + lane];

#pragma unroll 1                          // keep VGPR under the 128 cap
    for (int task = 0; task < 2; ++task) {
        const int row0 = blk * 16 + task * 8 + wave * 2;   // 2 consecutive rows

        double rsum[2];
#pragma unroll
        for (int r = 0; r < 2; ++r) {
            const f32x4* xr =
                reinterpret_cast<const f32x4*>(x + (size_t)(row0 + r) * DMODEL);
            f32x4 xv[8];
#pragma unroll
            for (int t = 0; t < 8; ++t) xv[t] = xr[t * 64 + lane];

            double a0 = 0.0, a1 = 0.0, a2 = 0.0, a3 = 0.0;
#pragma unroll
            for (int t = 0; t < 8; ++t) {
                a0 += (double)xv[t].x * (double)wv[t].x;
                a1 += (double)xv[t].y * (double)wv[t].y;
                a2 += (double)xv[t].z * (double)wv[t].z;
                a3 += (double)xv[t].w * (double)wv[t].w;
            }
            rsum[r] = (a0 + a1) + (a2 + a3);
        }

#pragma unroll
        for (int off = 32; off > 0; off >>= 1) {
            rsum[0] += __shfl_down(rsum[0], off, 64);
            rsum[1] += __shfl_down(rsum[1], off, 64);
        }

        if (lane == 0) {
#pragma unroll
            for (int r = 0; r < 2; ++r) {
                float l = (float)rsum[r];
                logits[row0 + r]  = l;
                weights[row0 + r] = 1.0f / (1.0f + expf(-l));
            }
        }
    }

    // ===================== Arrival (device scope) ==========================
    __threadfence();                      // make this block's stores visible
    __syncthreads();
    if (tid == 0)
        __hip_atomic_fetch_add(&ctr[mybatch], 1u,
                               __ATOMIC_RELEASE, __HIP_MEMORY_SCOPE_AGENT);

    if (blk > 512) return;                // free the CU for phase B

    // ======================= Phase B ======================================
    if (blk < 512) {
        // ---- top-K mask: half of 64-element chunk p = blk>>1 ----
        const int p    = blk >> 1;        // chunk 0..255
        const int h    = blk & 1;         // which 32-element half
        const int b    = p >> 6;          // batch (== blk>>7)
        const int eblk = p & 63;

        if (tid == 0) {
            while (__hip_atomic_load(&ctr[b], __ATOMIC_ACQUIRE,
                                     __HIP_MEMORY_SCOPE_AGENT) < BLOCKS_PER_BATCH)
                __builtin_amdgcn_s_sleep(2);
        }
        __syncthreads();
        __threadfence();                  // acquire for all threads

        const float* row = logits + b * SEQ;
        for (int j = tid; j < SEQ / 4; j += 256)
            reinterpret_cast<float4*>(L)[j] =
                reinterpret_cast<const float4*>(row)[j];
        __syncthreads();

        const int e     = tid & 31;
        const int slice = tid >> 5;       // 0..7
        const int i     = eblk * 64 + h * 32 + e;
        const float v   = L[i];

        int gt = 0, eq = 0;
        const int j0 = slice * (SEQ / 8); // 512-float slice, wave-uniform reads
#pragma unroll 4
        for (int j = j0; j < j0 + SEQ / 8; j += 4) {
            float4 q = *reinterpret_cast<const float4*>(&L[j]);
            gt += (q.x > v) + (q.y > v) + (q.z > v) + (q.w > v);
            eq += (q.x == v) + (q.y == v) + (q.z == v) + (q.w == v);
        }
        sh_gt[e][slice] = gt;
        sh_eq[e][slice] = eq;
        __syncthreads();

        if (slice == 0) {                 // threads 0..31
            int GT = 0, EQ = 0;
#pragma unroll
            for (int s = 0; s < 8; ++s) { GT += sh_gt[e][s]; EQ += sh_eq[e][s]; }
            float m;
            if (GT >= KSEL) {
                m = 0.0f;
            } else if (EQ == 1) {
                m = 1.0f;                 // unique value, strictly inside top-K
            } else {
                // Rare tie path: jax top_k takes ties in increasing index order.
                int lower = 0;
                for (int j = 0; j < i; ++j) lower += (L[j] == v);
                m = (GT + lower < KSEL) ? 1.0f : 0.0f;
            }
            mask[b * SEQ + i] = m;
        }
    } else {
        // ---- block 512: aux_loss = unbiased variance of all weights ----
        if (tid == 0) {
            for (int b2 = 0; b2 < BATCH; ++b2)
                while (__hip_atomic_load(&ctr[b2], __ATOMIC_ACQUIRE,
                                         __HIP_MEMORY_SCOPE_AGENT) < BLOCKS_PER_BATCH)
                    __builtin_amdgcn_s_sleep(2);
        }
        __syncthreads();
        __threadfence();

        const int n = BATCH * SEQ;
        double s = 0.0, s2 = 0.0;
        for (int j = tid; j < n; j += 256) {
            double w = (double)weights[j];
            s  += w;
            s2 += w * w;
        }
#pragma unroll
        for (int off = 32; off > 0; off >>= 1) {
            s  += __shfl_down(s,  off, 64);
            s2 += __shfl_down(s2, off, 64);
        }
        if (lane == 0) { shv[wave] = s; shv[wave + 4] = s2; }
        __syncthreads();
        if (tid == 0) {
            double S  = shv[0] + shv[1] + shv[2] + shv[3];
            double S2 = shv[4] + shv[5] + shv[6] + shv[7];
            double mean = S / n;
            double var  = (S2 - (double)n * mean * mean) / (double)(n - 1);
            *aux = (float)var;
        }
    }
}

extern "C" void kernel_launch(void* const* d_in, const int* in_sizes, int n_in,
                              void* d_out, int out_size, void* d_ws, size_t ws_size,
                              hipStream_t stream) {
    const float* x      = (const float*)d_in[0];   // [4,4096,2048] f32
    const float* gate_w = (const float*)d_in[1];   // [2048] f32

    float* out     = (float*)d_out;
    float* mask    = out;                          // [4,4096,1]
    float* weights = out + BATCH * SEQ;            // [4,4096,1]
    float* aux     = out + 2 * BATCH * SEQ;        // [1]

    float* logits     = (float*)d_ws;                              // 64 KiB
    unsigned int* ctr = (unsigned int*)((char*)d_ws + SEQ * BATCH * 4); // 4 u32

    // Per-call counter reset (graph-capturable, deterministic across replays).
    hipMemsetAsync(ctr, 0, BATCH * sizeof(unsigned int), stream);

    fused_kernel<<<dim3(NBLK), dim3(256), 0, stream>>>(
        x, gate_w, logits, ctr, mask, weights, aux);
}

// Round 9
// 295.820 us; speedup vs baseline: 1.1245x; 1.1245x over previous
//
#include <hip/hip_runtime.h>
#include <hip/hip_bf16.h>

// Problem constants (from reference setup_inputs: b=4, s=4096, d=2048, CAPACITY=0.5)
#define BATCH 4
#define SEQ   4096
#define DMODEL 2048
#define KSEL  2048            // max(1, int(SEQ*0.5))
#define NBLK  1024
#define BLOCKS_PER_BATCH 256  // 4096 rows / 16 rows-per-block

typedef float f32x4 __attribute__((ext_vector_type(4)));

// ---------------------------------------------------------------------------
// Fused kernel (R8 structure, spill fix): phase A computes logits+weights
// (16 rows/block, exact R4 2-row-per-wave summation order -> bit-identical
// logits for top-k safety), then a device-scope per-batch arrival barrier,
// then phase B:
//   blocks 0..511 : top-K mask (half a 64-element chunk each)
//   block  512    : aux variance
//   blocks 513+   : exit (free CUs for phase B)
// R8's __launch_bounds__(256,4) capped VGPR at 64 -> xv/wv spilled to
// scratch (WRITE_SIZE 60 MB, 332 us). Natural allocation (~110 VGPR, as in
// R4's K1) still yields 4 waves/EU -> 4 blocks/CU without spilling.
// Deadlock safety: consumers spin on PER-BATCH counters; producers for a
// batch are dispatched before (or alongside) its consumers, and waiting
// blocks 0..512 leave >=255 block slots free for remaining producers.
// ---------------------------------------------------------------------------
__global__ __launch_bounds__(256) void fused_kernel(
    const float* __restrict__ x,
    const float* __restrict__ gate_w,
    float* __restrict__ logits,          // d_ws
    unsigned int* __restrict__ ctr,      // d_ws + 64KiB, memset to 0 per call
    float* __restrict__ mask,            // d_out
    float* __restrict__ weights,         // d_out + 16384
    float* __restrict__ aux)             // d_out + 32768
{
    const int tid  = threadIdx.x;
    const int wave = tid >> 6;
    const int lane = tid & 63;
    const int blk  = blockIdx.x;
    const int mybatch = blk >> 8;        // 16 rows/block, 256 blocks/batch

    __shared__ float L[SEQ];             // 16 KiB (phase B)
    __shared__ int sh_gt[32][9];         // stride 9 -> conflict-free combines
    __shared__ int sh_eq[32][9];
    __shared__ double shv[8];

    // ======================= Phase A: logits ===============================
    const f32x4* wr = reinterpret_cast<const f32x4*>(gate_w);
    f32x4 wv[8];
#pragma unroll
    for (int t = 0; t < 8; ++t) wv[t] = wr[t * 64 + lane];

#pragma unroll 1
    for (int task = 0; task < 2; ++task) {
        const int row0 = blk * 16 + task * 8 + wave * 2;   // 2 consecutive rows

        double rsum[2];
#pragma unroll
        for (int r = 0; r < 2; ++r) {
            const f32x4* xr =
                reinterpret_cast<const f32x4*>(x + (size_t)(row0 + r) * DMODEL);
            f32x4 xv[8];
#pragma unroll
            for (int t = 0; t < 8; ++t) xv[t] = xr[t * 64 + lane];

            double a0 = 0.0, a1 = 0.0, a2 = 0.0, a3 = 0.0;
#pragma unroll
            for (int t = 0; t < 8; ++t) {
                a0 += (double)xv[t].x * (double)wv[t].x;
                a1 += (double)xv[t].y * (double)wv[t].y;
                a2 += (double)xv[t].z * (double)wv[t].z;
                a3 += (double)xv[t].w * (double)wv[t].w;
            }
            rsum[r] = (a0 + a1) + (a2 + a3);
        }

#pragma unroll
        for (int off = 32; off > 0; off >>= 1) {
            rsum[0] += __shfl_down(rsum[0], off, 64);
            rsum[1] += __shfl_down(rsum[1], off, 64);
        }

        if (lane == 0) {
#pragma unroll
            for (int r = 0; r < 2; ++r) {
                float l = (float)rsum[r];
                logits[row0 + r]  = l;
                weights[row0 + r] = 1.0f / (1.0f + expf(-l));
            }
        }
    }

    // ===================== Arrival (device scope) ==========================
    __threadfence();                      // make this block's stores visible
    __syncthreads();
    if (tid == 0)
        __hip_atomic_fetch_add(&ctr[mybatch], 1u,
                               __ATOMIC_RELEASE, __HIP_MEMORY_SCOPE_AGENT);

    if (blk > 512) return;                // free the CU for phase B

    // ======================= Phase B ======================================
    if (blk < 512) {
        // ---- top-K mask: half of 64-element chunk p = blk>>1 ----
        const int p    = blk >> 1;        // chunk 0..255
        const int h    = blk & 1;         // which 32-element half
        const int b    = p >> 6;          // batch (== blk>>7)
        const int eblk = p & 63;

        if (tid == 0) {
            while (__hip_atomic_load(&ctr[b], __ATOMIC_ACQUIRE,
                                     __HIP_MEMORY_SCOPE_AGENT) < BLOCKS_PER_BATCH)
                __builtin_amdgcn_s_sleep(2);
        }
        __syncthreads();
        __threadfence();                  // acquire for all threads

        const float* row = logits + b * SEQ;
        for (int j = tid; j < SEQ / 4; j += 256)
            reinterpret_cast<float4*>(L)[j] =
                reinterpret_cast<const float4*>(row)[j];
        __syncthreads();

        const int e     = tid & 31;
        const int slice = tid >> 5;       // 0..7
        const int i     = eblk * 64 + h * 32 + e;
        const float v   = L[i];

        int gt = 0, eq = 0;
        const int j0 = slice * (SEQ / 8); // 512-float slice, wave-uniform reads
#pragma unroll 4
        for (int j = j0; j < j0 + SEQ / 8; j += 4) {
            float4 q = *reinterpret_cast<const float4*>(&L[j]);
            gt += (q.x > v) + (q.y > v) + (q.z > v) + (q.w > v);
            eq += (q.x == v) + (q.y == v) + (q.z == v) + (q.w == v);
        }
        sh_gt[e][slice] = gt;
        sh_eq[e][slice] = eq;
        __syncthreads();

        if (slice == 0) {                 // threads 0..31
            int GT = 0, EQ = 0;
#pragma unroll
            for (int s = 0; s < 8; ++s) { GT += sh_gt[e][s]; EQ += sh_eq[e][s]; }
            float m;
            if (GT >= KSEL) {
                m = 0.0f;
            } else if (EQ == 1) {
                m = 1.0f;                 // unique value, strictly inside top-K
            } else {
                // Rare tie path: jax top_k takes ties in increasing index order.
                int lower = 0;
                for (int j = 0; j < i; ++j) lower += (L[j] == v);
                m = (GT + lower < KSEL) ? 1.0f : 0.0f;
            }
            mask[b * SEQ + i] = m;
        }
    } else {
        // ---- block 512: aux_loss = unbiased variance of all weights ----
        if (tid == 0) {
            for (int b2 = 0; b2 < BATCH; ++b2)
                while (__hip_atomic_load(&ctr[b2], __ATOMIC_ACQUIRE,
                                         __HIP_MEMORY_SCOPE_AGENT) < BLOCKS_PER_BATCH)
                    __builtin_amdgcn_s_sleep(2);
        }
        __syncthreads();
        __threadfence();

        const int n = BATCH * SEQ;
        double s = 0.0, s2 = 0.0;
        for (int j = tid; j < n; j += 256) {
            double w = (double)weights[j];
            s  += w;
            s2 += w * w;
        }
#pragma unroll
        for (int off = 32; off > 0; off >>= 1) {
            s  += __shfl_down(s,  off, 64);
            s2 += __shfl_down(s2, off, 64);
        }
        if (lane == 0) { shv[wave] = s; shv[wave + 4] = s2; }
        __syncthreads();
        if (tid == 0) {
            double S  = shv[0] + shv[1] + shv[2] + shv[3];
            double S2 = shv[4] + shv[5] + shv[6] + shv[7];
            double mean = S / n;
            double var  = (S2 - (double)n * mean * mean) / (double)(n - 1);
            *aux = (float)var;
        }
    }
}

extern "C" void kernel_launch(void* const* d_in, const int* in_sizes, int n_in,
                              void* d_out, int out_size, void* d_ws, size_t ws_size,
                              hipStream_t stream) {
    const float* x      = (const float*)d_in[0];   // [4,4096,2048] f32
    const float* gate_w = (const float*)d_in[1];   // [2048] f32

    float* out     = (float*)d_out;
    float* mask    = out;                          // [4,4096,1]
    float* weights = out + BATCH * SEQ;            // [4,4096,1]
    float* aux     = out + 2 * BATCH * SEQ;        // [1]

    float* logits     = (float*)d_ws;                              // 64 KiB
    unsigned int* ctr = (unsigned int*)((char*)d_ws + SEQ * BATCH * 4); // 4 u32

    // Per-call counter reset (graph-capturable, deterministic across replays).
    hipMemsetAsync(ctr, 0, BATCH * sizeof(unsigned int), stream);

    fused_kernel<<<dim3(NBLK), dim3(256), 0, stream>>>(
        x, gate_w, logits, ctr, mask, weights, aux);
}

// Round 10
// 42.839 us; speedup vs baseline: 7.7649x; 6.9054x over previous
//
#include <hip/hip_runtime.h>
#include <hip/hip_bf16.h>

// Problem constants (from reference setup_inputs: b=4, s=4096, d=2048, CAPACITY=0.5)
#define BATCH 4
#define SEQ   4096
#define DMODEL 2048
#define KSEL  2048   // max(1, int(SEQ*0.5))

typedef float f32x4 __attribute__((ext_vector_type(4)));

// ---------------------------------------------------------------------------
// Kernel 1: logits = x @ gate_w (fp64 accumulate), weights = sigmoid(logits)
// 1024 blocks x 256 threads; each 64-lane wave owns 4 consecutive rows.
// x is loaded in 2 chunks of (4 rows x 4 float4) so only 16 x-float4 are
// live at once (~64 VGPR) -> natural allocation ~140 VGPR, no launch-bounds
// cap (R3's spill trap), ~3 blocks/CU -> nearly the whole grid resident in
// one generation. gate_w (8 float4/lane) loaded once per wave, amortized
// over 4 rows; one 4-chain reduce tail per 4 rows.
// Per-accumulator FMA order is t-ascending, identical to R2/R4 ->
// bit-identical logits (top-k ranking stability).
// ---------------------------------------------------------------------------
__global__ __launch_bounds__(256) void logits_kernel(
    const float* __restrict__ x,
    const float* __restrict__ gate_w,
    float* __restrict__ logits,     // [BATCH*SEQ] in workspace
    float* __restrict__ weights)    // [BATCH*SEQ] -> d_out + BATCH*SEQ
{
    const int wave = threadIdx.x >> 6;
    const int lane = threadIdx.x & 63;
    const int wid  = blockIdx.x * 4 + wave;          // 0 .. 4095
    const int row0 = wid * 4;                        // 4 consecutive rows

    const f32x4* wr = reinterpret_cast<const f32x4*>(gate_w);
    f32x4 wv[8];
#pragma unroll
    for (int t = 0; t < 8; ++t) wv[t] = wr[t * 64 + lane];

    const f32x4* xr0 = reinterpret_cast<const f32x4*>(x + (size_t)(row0 + 0) * DMODEL);
    const f32x4* xr1 = reinterpret_cast<const f32x4*>(x + (size_t)(row0 + 1) * DMODEL);
    const f32x4* xr2 = reinterpret_cast<const f32x4*>(x + (size_t)(row0 + 2) * DMODEL);
    const f32x4* xr3 = reinterpret_cast<const f32x4*>(x + (size_t)(row0 + 3) * DMODEL);

    double a0[4] = {0,0,0,0}, a1[4] = {0,0,0,0}, a2[4] = {0,0,0,0}, a3[4] = {0,0,0,0};

#pragma unroll
    for (int c = 0; c < 2; ++c) {
        // 16 loads in flight (4 rows x 4 float4), 64 B/lane
        f32x4 xv0[4], xv1[4], xv2[4], xv3[4];
#pragma unroll
        for (int t = 0; t < 4; ++t) xv0[t] = xr0[(c * 4 + t) * 64 + lane];
#pragma unroll
        for (int t = 0; t < 4; ++t) xv1[t] = xr1[(c * 4 + t) * 64 + lane];
#pragma unroll
        for (int t = 0; t < 4; ++t) xv2[t] = xr2[(c * 4 + t) * 64 + lane];
#pragma unroll
        for (int t = 0; t < 4; ++t) xv3[t] = xr3[(c * 4 + t) * 64 + lane];

#pragma unroll
        for (int t = 0; t < 4; ++t) {
            const f32x4 w = wv[c * 4 + t];
            a0[0] += (double)xv0[t].x * (double)w.x;
            a0[1] += (double)xv0[t].y * (double)w.y;
            a0[2] += (double)xv0[t].z * (double)w.z;
            a0[3] += (double)xv0[t].w * (double)w.w;
            a1[0] += (double)xv1[t].x * (double)w.x;
            a1[1] += (double)xv1[t].y * (double)w.y;
            a1[2] += (double)xv1[t].z * (double)w.z;
            a1[3] += (double)xv1[t].w * (double)w.w;
            a2[0] += (double)xv2[t].x * (double)w.x;
            a2[1] += (double)xv2[t].y * (double)w.y;
            a2[2] += (double)xv2[t].z * (double)w.z;
            a2[3] += (double)xv2[t].w * (double)w.w;
            a3[0] += (double)xv3[t].x * (double)w.x;
            a3[1] += (double)xv3[t].y * (double)w.y;
            a3[2] += (double)xv3[t].z * (double)w.z;
            a3[3] += (double)xv3[t].w * (double)w.w;
        }
    }

    double rsum[4];
    rsum[0] = (a0[0] + a0[1]) + (a0[2] + a0[3]);
    rsum[1] = (a1[0] + a1[1]) + (a1[2] + a1[3]);
    rsum[2] = (a2[0] + a2[1]) + (a2[2] + a2[3]);
    rsum[3] = (a3[0] + a3[1]) + (a3[2] + a3[3]);

    // 64-lane reduction, 4 independent fp64 chains interleaved
#pragma unroll
    for (int off = 32; off > 0; off >>= 1) {
#pragma unroll
        for (int r = 0; r < 4; ++r)
            rsum[r] += __shfl_down(rsum[r], off, 64);
    }

    if (lane == 0) {
#pragma unroll
        for (int r = 0; r < 4; ++r) {
            float l = (float)rsum[r];
            logits[row0 + r]  = l;
            weights[row0 + r] = 1.0f / (1.0f + expf(-l));
        }
    }
}

// ---------------------------------------------------------------------------
// Kernel 2 (merged select + finalize), 513 blocks x 512 threads:
//   blocks 0..511 : top-K mask; block handles 32 elements (half of 64-chunk
//                   p = blk>>1, half h = blk&1). Thread (e = tid&31,
//                   slice = tid>>5, 16 slices x 256 floats). Each wave spans
//                   2 slices -> 2 concurrent LDS broadcasts (conflict-free).
//   block 512     : aux_loss = unbiased variance of weights (fp64).
// Tie-break matches jax.lax.top_k (lower index wins) via rare-path recount.
// ---------------------------------------------------------------------------
__global__ __launch_bounds__(512) void select_finalize_kernel(
    const float* __restrict__ logits,
    const float* __restrict__ weights,
    float* __restrict__ mask,       // -> d_out + 0
    float* __restrict__ aux)        // -> d_out + 2*BATCH*SEQ
{
    if (blockIdx.x == 512) {
        // ---- variance block (512 threads, fp64) ----
        const int n = BATCH * SEQ;
        double s = 0.0, s2 = 0.0;
        for (int i = threadIdx.x; i < n; i += 512) {
            double w = (double)weights[i];
            s  += w;
            s2 += w * w;
        }
#pragma unroll
        for (int off = 32; off > 0; off >>= 1) {
            s  += __shfl_down(s,  off, 64);
            s2 += __shfl_down(s2, off, 64);
        }
        __shared__ double sh[16];
        const int wid  = threadIdx.x >> 6;
        const int lane = threadIdx.x & 63;
        if (lane == 0) { sh[wid] = s; sh[wid + 8] = s2; }
        __syncthreads();
        if (threadIdx.x == 0) {
            double S = 0.0, S2 = 0.0;
#pragma unroll
            for (int w = 0; w < 8; ++w) { S += sh[w]; S2 += sh[w + 8]; }
            double mean = S / n;
            double var  = (S2 - (double)n * mean * mean) / (double)(n - 1);
            *aux = (float)var;
        }
        return;
    }

    const int p    = blockIdx.x >> 1;    // 64-element chunk 0..255
    const int h    = blockIdx.x & 1;     // which 32-element half
    const int b    = p >> 6;             // batch
    const int eblk = p & 63;

    __shared__ float L[SEQ];             // 16 KiB row
    __shared__ int sh_gt[32][17];        // [e][slice], stride 17 -> conflict-free
    __shared__ int sh_eq[32][17];

    const float* row = logits + b * SEQ;
    for (int i = threadIdx.x; i < SEQ / 4; i += 512)
        reinterpret_cast<float4*>(L)[i] =
            reinterpret_cast<const float4*>(row)[i];
    __syncthreads();

    const int e     = threadIdx.x & 31;
    const int slice = threadIdx.x >> 5;  // 0..15
    const int i     = eblk * 64 + h * 32 + e;
    const float v   = L[i];

    int gt = 0, eq = 0;
    const int j0 = slice * (SEQ / 16);   // 256-float slice
#pragma unroll 4
    for (int j = j0; j < j0 + SEQ / 16; j += 4) {
        float4 q = *reinterpret_cast<const float4*>(&L[j]);
        gt += (q.x > v) + (q.y > v) + (q.z > v) + (q.w > v);
        eq += (q.x == v) + (q.y == v) + (q.z == v) + (q.w == v);
    }
    sh_gt[e][slice] = gt;
    sh_eq[e][slice] = eq;
    __syncthreads();

    if (slice == 0) {                    // threads 0..31
        int GT = 0, EQ = 0;
#pragma unroll
        for (int s = 0; s < 16; ++s) { GT += sh_gt[e][s]; EQ += sh_eq[e][s]; }
        float m;
        if (GT >= KSEL) {
            m = 0.0f;
        } else if (EQ == 1) {
            m = 1.0f;                    // unique value, strictly inside top-K
        } else {
            // Rare tie path: jax top_k takes ties in increasing index order.
            int lower = 0;
            for (int j = 0; j < i; ++j) lower += (L[j] == v);
            m = (GT + lower < KSEL) ? 1.0f : 0.0f;
        }
        mask[b * SEQ + i] = m;
    }
}

extern "C" void kernel_launch(void* const* d_in, const int* in_sizes, int n_in,
                              void* d_out, int out_size, void* d_ws, size_t ws_size,
                              hipStream_t stream) {
    const float* x      = (const float*)d_in[0];   // [4,4096,2048] f32
    const float* gate_w = (const float*)d_in[1];   // [2048] f32

    float* out     = (float*)d_out;
    float* mask    = out;                          // [4,4096,1]
    float* weights = out + BATCH * SEQ;            // [4,4096,1]
    float* aux     = out + 2 * BATCH * SEQ;        // [1]

    float* logits = (float*)d_ws;                  // [4*4096] scratch

    // K1: logits + weights  (1024 blocks x 4 waves x 4 rows/wave = 16384 rows)
    logits_kernel<<<dim3(BATCH * SEQ / 16), dim3(256), 0, stream>>>(
        x, gate_w, logits, weights);

    // K2: top-K mask (512 blocks x 32 elems) + variance (1 block)
    select_finalize_kernel<<<dim3(513), dim3(512), 0, stream>>>(
        logits, weights, mask, aux);
}

// Round 11
// 42.441 us; speedup vs baseline: 7.8377x; 1.0094x over previous
//
#include <hip/hip_runtime.h>
#include <hip/hip_bf16.h>

// Problem constants (from reference setup_inputs: b=4, s=4096, d=2048, CAPACITY=0.5)
#define BATCH 4
#define SEQ   4096
#define DMODEL 2048
#define KSEL  2048   // max(1, int(SEQ*0.5))

typedef float f32x4 __attribute__((ext_vector_type(4)));

// ---------------------------------------------------------------------------
// Kernel 1 [EXACT R4 form — best measured; do not touch without evidence]:
// logits = x @ gate_w (fp64 accumulate), weights = sigmoid(logits).
// 2048 blocks x 256 threads; each 64-lane wave owns 2 consecutive rows.
// gate_w (8 float4/lane) loaded once per wave. Per row: 8 float4 x-loads
// then 32 fp64 FMAs in 4 independent chains. ~110 VGPR -> 4 waves/EU, no
// spill. Per-row summation order identical across rounds -> bit-identical
// logits (top-k ranking stability).
// ---------------------------------------------------------------------------
__global__ __launch_bounds__(256) void logits_kernel(
    const float* __restrict__ x,
    const float* __restrict__ gate_w,
    float* __restrict__ logits,     // [BATCH*SEQ] in workspace
    float* __restrict__ weights)    // [BATCH*SEQ] -> d_out + BATCH*SEQ
{
    const int wave = threadIdx.x >> 6;
    const int lane = threadIdx.x & 63;
    const int wid  = blockIdx.x * 4 + wave;          // 0 .. 8191
    const int row0 = wid * 2;                        // 2 consecutive rows

    const f32x4* wr = reinterpret_cast<const f32x4*>(gate_w);
    f32x4 wv[8];
#pragma unroll
    for (int t = 0; t < 8; ++t) wv[t] = wr[t * 64 + lane];

    double rsum[2];
#pragma unroll
    for (int r = 0; r < 2; ++r) {
        const f32x4* xr =
            reinterpret_cast<const f32x4*>(x + (size_t)(row0 + r) * DMODEL);
        f32x4 xv[8];
#pragma unroll
        for (int t = 0; t < 8; ++t) xv[t] = xr[t * 64 + lane];

        double a0 = 0.0, a1 = 0.0, a2 = 0.0, a3 = 0.0;
#pragma unroll
        for (int t = 0; t < 8; ++t) {
            a0 += (double)xv[t].x * (double)wv[t].x;
            a1 += (double)xv[t].y * (double)wv[t].y;
            a2 += (double)xv[t].z * (double)wv[t].z;
            a3 += (double)xv[t].w * (double)wv[t].w;
        }
        rsum[r] = (a0 + a1) + (a2 + a3);
    }

    // 64-lane reduction, 2 independent fp64 chains interleaved
#pragma unroll
    for (int off = 32; off > 0; off >>= 1) {
        rsum[0] += __shfl_down(rsum[0], off, 64);
        rsum[1] += __shfl_down(rsum[1], off, 64);
    }

    if (lane == 0) {
#pragma unroll
        for (int r = 0; r < 2; ++r) {
            float l = (float)rsum[r];
            logits[row0 + r]  = l;
            weights[row0 + r] = 1.0f / (1.0f + expf(-l));
        }
    }
}

// ---------------------------------------------------------------------------
// Kernel 2 (merged select + finalize), 513 blocks x 512 threads
// [isolated change vs R4: 2 blocks per 64-chunk -> 2 blocks/CU]:
//   blocks 0..511 : top-K mask; block handles 32 elements (half of 64-chunk
//                   p = blk>>1, half h = blk&1). Thread (e = tid&31,
//                   slice = tid>>5, 16 slices x 256 floats). Wave-uniform
//                   float4 LDS broadcasts, conflict-free.
//   block 512     : aux_loss = unbiased variance of weights (fp64).
// Tie-break matches jax.lax.top_k (lower index wins) via rare-path recount.
// ---------------------------------------------------------------------------
__global__ __launch_bounds__(512) void select_finalize_kernel(
    const float* __restrict__ logits,
    const float* __restrict__ weights,
    float* __restrict__ mask,       // -> d_out + 0
    float* __restrict__ aux)        // -> d_out + 2*BATCH*SEQ
{
    if (blockIdx.x == 512) {
        // ---- variance block (512 threads, fp64) ----
        const int n = BATCH * SEQ;
        double s = 0.0, s2 = 0.0;
        for (int i = threadIdx.x; i < n; i += 512) {
            double w = (double)weights[i];
            s  += w;
            s2 += w * w;
        }
#pragma unroll
        for (int off = 32; off > 0; off >>= 1) {
            s  += __shfl_down(s,  off, 64);
            s2 += __shfl_down(s2, off, 64);
        }
        __shared__ double sh[16];
        const int wid  = threadIdx.x >> 6;
        const int lane = threadIdx.x & 63;
        if (lane == 0) { sh[wid] = s; sh[wid + 8] = s2; }
        __syncthreads();
        if (threadIdx.x == 0) {
            double S = 0.0, S2 = 0.0;
#pragma unroll
            for (int w = 0; w < 8; ++w) { S += sh[w]; S2 += sh[w + 8]; }
            double mean = S / n;
            double var  = (S2 - (double)n * mean * mean) / (double)(n - 1);
            *aux = (float)var;
        }
        return;
    }

    const int p    = blockIdx.x >> 1;    // 64-element chunk 0..255
    const int h    = blockIdx.x & 1;     // which 32-element half
    const int b    = p >> 6;             // batch
    const int eblk = p & 63;

    __shared__ float L[SEQ];             // 16 KiB row
    __shared__ int sh_gt[32][17];        // [e][slice], stride 17 -> conflict-free
    __shared__ int sh_eq[32][17];

    const float* row = logits + b * SEQ;
    for (int i = threadIdx.x; i < SEQ / 4; i += 512)
        reinterpret_cast<float4*>(L)[i] =
            reinterpret_cast<const float4*>(row)[i];
    __syncthreads();

    const int e     = threadIdx.x & 31;
    const int slice = threadIdx.x >> 5;  // 0..15
    const int i     = eblk * 64 + h * 32 + e;
    const float v   = L[i];

    int gt = 0, eq = 0;
    const int j0 = slice * (SEQ / 16);   // 256-float slice
#pragma unroll 4
    for (int j = j0; j < j0 + SEQ / 16; j += 4) {
        float4 q = *reinterpret_cast<const float4*>(&L[j]);
        gt += (q.x > v) + (q.y > v) + (q.z > v) + (q.w > v);
        eq += (q.x == v) + (q.y == v) + (q.z == v) + (q.w == v);
    }
    sh_gt[e][slice] = gt;
    sh_eq[e][slice] = eq;
    __syncthreads();

    if (slice == 0) {                    // threads 0..31
        int GT = 0, EQ = 0;
#pragma unroll
        for (int s = 0; s < 16; ++s) { GT += sh_gt[e][s]; EQ += sh_eq[e][s]; }
        float m;
        if (GT >= KSEL) {
            m = 0.0f;
        } else if (EQ == 1) {
            m = 1.0f;                    // unique value, strictly inside top-K
        } else {
            // Rare tie path: jax top_k takes ties in increasing index order.
            int lower = 0;
            for (int j = 0; j < i; ++j) lower += (L[j] == v);
            m = (GT + lower < KSEL) ? 1.0f : 0.0f;
        }
        mask[b * SEQ + i] = m;
    }
}

extern "C" void kernel_launch(void* const* d_in, const int* in_sizes, int n_in,
                              void* d_out, int out_size, void* d_ws, size_t ws_size,
                              hipStream_t stream) {
    const float* x      = (const float*)d_in[0];   // [4,4096,2048] f32
    const float* gate_w = (const float*)d_in[1];   // [2048] f32

    float* out     = (float*)d_out;
    float* mask    = out;                          // [4,4096,1]
    float* weights = out + BATCH * SEQ;            // [4,4096,1]
    float* aux     = out + 2 * BATCH * SEQ;        // [1]

    float* logits = (float*)d_ws;                  // [4*4096] scratch

    // K1: logits + weights  (2048 blocks x 4 waves x 2 rows/wave = 16384 rows)
    logits_kernel<<<dim3(BATCH * SEQ / 8), dim3(256), 0, stream>>>(
        x, gate_w, logits, weights);

    // K2: top-K mask (512 blocks x 32 elems) + variance (1 block)
    select_finalize_kernel<<<dim3(513), dim3(512), 0, stream>>>(
        logits, weights, mask, aux);
}

// Round 12
// 41.262 us; speedup vs baseline: 8.0615x; 1.0286x over previous
//
#include <hip/hip_runtime.h>
#include <hip/hip_bf16.h>

// Problem constants (from reference setup_inputs: b=4, s=4096, d=2048, CAPACITY=0.5)
#define BATCH 4
#define SEQ   4096
#define DMODEL 2048
#define KSEL  2048   // max(1, int(SEQ*0.5))

typedef float f32x4 __attribute__((ext_vector_type(4)));

// ---------------------------------------------------------------------------
// Kernel 1 [EXACT R4 form — best measured; do not touch without evidence]:
// logits = x @ gate_w (fp64 accumulate), weights = sigmoid(logits).
// 2048 blocks x 256 threads; each 64-lane wave owns 2 consecutive rows.
// gate_w (8 float4/lane) loaded once per wave. Per row: 8 float4 x-loads
// then 32 fp64 FMAs in 4 independent chains. ~110 VGPR -> 4 waves/EU, no
// spill. Per-row summation order identical across rounds -> bit-identical
// logits (top-k ranking stability).
// ---------------------------------------------------------------------------
__global__ __launch_bounds__(256) void logits_kernel(
    const float* __restrict__ x,
    const float* __restrict__ gate_w,
    float* __restrict__ logits,     // [BATCH*SEQ] in workspace
    float* __restrict__ weights)    // [BATCH*SEQ] -> d_out + BATCH*SEQ
{
    const int wave = threadIdx.x >> 6;
    const int lane = threadIdx.x & 63;
    const int wid  = blockIdx.x * 4 + wave;          // 0 .. 8191
    const int row0 = wid * 2;                        // 2 consecutive rows

    const f32x4* wr = reinterpret_cast<const f32x4*>(gate_w);
    f32x4 wv[8];
#pragma unroll
    for (int t = 0; t < 8; ++t) wv[t] = wr[t * 64 + lane];

    double rsum[2];
#pragma unroll
    for (int r = 0; r < 2; ++r) {
        const f32x4* xr =
            reinterpret_cast<const f32x4*>(x + (size_t)(row0 + r) * DMODEL);
        f32x4 xv[8];
#pragma unroll
        for (int t = 0; t < 8; ++t) xv[t] = xr[t * 64 + lane];

        double a0 = 0.0, a1 = 0.0, a2 = 0.0, a3 = 0.0;
#pragma unroll
        for (int t = 0; t < 8; ++t) {
            a0 += (double)xv[t].x * (double)wv[t].x;
            a1 += (double)xv[t].y * (double)wv[t].y;
            a2 += (double)xv[t].z * (double)wv[t].z;
            a3 += (double)xv[t].w * (double)wv[t].w;
        }
        rsum[r] = (a0 + a1) + (a2 + a3);
    }

    // 64-lane reduction, 2 independent fp64 chains interleaved
#pragma unroll
    for (int off = 32; off > 0; off >>= 1) {
        rsum[0] += __shfl_down(rsum[0], off, 64);
        rsum[1] += __shfl_down(rsum[1], off, 64);
    }

    if (lane == 0) {
#pragma unroll
        for (int r = 0; r < 2; ++r) {
            float l = (float)rsum[r];
            logits[row0 + r]  = l;
            weights[row0 + r] = 1.0f / (1.0f + expf(-l));
        }
    }
}

// ---------------------------------------------------------------------------
// Kernel 2 (select + finalize), 257 blocks x 512 threads — ballot/popcount:
//   blocks 0..255 : top-K mask for 64 v-elements (chunk vchunk = blk&63 of
//                   batch b = blk>>6). ROW data lives in per-lane registers
//                   (lane l of wave w holds row[w*512 + c*64 + l], c=0..7);
//                   each v is wave-uniform, so ONE v_cmp compares v against
//                   64 row elements and __popcll(__ballot()) accumulates in
//                   SALU — no LDS row staging, no per-lane adders.
//                   Per-wave partial (gt,eq) packed into u32 -> 2 KiB LDS
//                   table -> combined by threads 0..63.
//   block 256     : aux_loss = unbiased variance of weights (fp64).
// Tie-break matches jax.lax.top_k (lower index wins) via rare-path rescan
// of the (L2-hot) logits row from global.
// ---------------------------------------------------------------------------
__global__ __launch_bounds__(512) void select_finalize_kernel(
    const float* __restrict__ logits,
    const float* __restrict__ weights,
    float* __restrict__ mask,       // -> d_out + 0
    float* __restrict__ aux)        // -> d_out + 2*BATCH*SEQ
{
    if (blockIdx.x == 256) {
        // ---- variance block (512 threads, fp64) ----
        const int n = BATCH * SEQ;
        double s = 0.0, s2 = 0.0;
        for (int i = threadIdx.x; i < n; i += 512) {
            double w = (double)weights[i];
            s  += w;
            s2 += w * w;
        }
#pragma unroll
        for (int off = 32; off > 0; off >>= 1) {
            s  += __shfl_down(s,  off, 64);
            s2 += __shfl_down(s2, off, 64);
        }
        __shared__ double sh[16];
        const int wid  = threadIdx.x >> 6;
        const int lane = threadIdx.x & 63;
        if (lane == 0) { sh[wid] = s; sh[wid + 8] = s2; }
        __syncthreads();
        if (threadIdx.x == 0) {
            double S = 0.0, S2 = 0.0;
#pragma unroll
            for (int w = 0; w < 8; ++w) { S += sh[w]; S2 += sh[w + 8]; }
            double mean = S / n;
            double var  = (S2 - (double)n * mean * mean) / (double)(n - 1);
            *aux = (float)var;
        }
        return;
    }

    const int blk    = blockIdx.x;
    const int b      = blk >> 6;         // batch
    const int vchunk = blk & 63;         // 64-element v chunk
    const float* row = logits + b * SEQ; // L2-hot from K1

    const int w = threadIdx.x >> 6;      // wave 0..7
    const int l = threadIdx.x & 63;      // lane

    __shared__ unsigned int C[64][9];    // [k][wave] packed partials, padded

    // Row slice into registers: 8 coalesced b32 loads per lane.
    float rv[8];
#pragma unroll
    for (int c = 0; c < 8; ++c) rv[c] = row[w * 512 + c * 64 + l];

    // Per-wave partial counts for each of the 64 v's.
    // v address is wave-uniform -> scalar load; cmp via ballot, count in SALU.
#pragma unroll 8
    for (int k = 0; k < 64; ++k) {
        const float vv = row[vchunk * 64 + k];
        int gt = 0, eq = 0;
#pragma unroll
        for (int c = 0; c < 8; ++c) {
            gt += __popcll(__ballot(rv[c] > vv));
            eq += __popcll(__ballot(rv[c] == vv));
        }
        if (l == 0) C[k][w] = ((unsigned)gt << 16) | (unsigned)eq;
    }
    __syncthreads();

    if (threadIdx.x < 64) {
        const int k = threadIdx.x;
        unsigned GT = 0, EQ = 0;
#pragma unroll
        for (int ww = 0; ww < 8; ++ww) {
            const unsigned p = C[k][ww];
            GT += p >> 16;
            EQ += p & 0xffffu;
        }
        const int i    = vchunk * 64 + k;
        const float vv = row[i];
        float m;
        if (GT >= KSEL) {
            m = 0.0f;
        } else if (EQ == 1) {
            m = 1.0f;                    // unique value, strictly inside top-K
        } else {
            // Rare tie path: jax top_k takes ties in increasing index order.
            int lower = 0;
            for (int j = 0; j < i; ++j) lower += (row[j] == vv);
            m = (GT + lower < KSEL) ? 1.0f : 0.0f;
        }
        mask[b * SEQ + i] = m;
    }
}

extern "C" void kernel_launch(void* const* d_in, const int* in_sizes, int n_in,
                              void* d_out, int out_size, void* d_ws, size_t ws_size,
                              hipStream_t stream) {
    const float* x      = (const float*)d_in[0];   // [4,4096,2048] f32
    const float* gate_w = (const float*)d_in[1];   // [2048] f32

    float* out     = (float*)d_out;
    float* mask    = out;                          // [4,4096,1]
    float* weights = out + BATCH * SEQ;            // [4,4096,1]
    float* aux     = out + 2 * BATCH * SEQ;        // [1]

    float* logits = (float*)d_ws;                  // [4*4096] scratch

    // K1: logits + weights  (2048 blocks x 4 waves x 2 rows/wave = 16384 rows)
    logits_kernel<<<dim3(BATCH * SEQ / 8), dim3(256), 0, stream>>>(
        x, gate_w, logits, weights);

    // K2: top-K mask (256 blocks x 64 v's, ballot/popcount) + variance (1 block)
    select_finalize_kernel<<<dim3(257), dim3(512), 0, stream>>>(
        logits, weights, mask, aux);
}